// Round 9
// baseline (1142.239 us; speedup 1.0000x reference)
//
#include <hip/hip_runtime.h>
#include <hip/hip_bf16.h>
#include <stdint.h>

// cheb_conv_withSAt: out[b,m,o,t] = relu( sum_k sum_f Theta[k,f,o] *
//                       sum_n cheb[k,n,m]*At[b,n,m]*x[b,n,f,t] )
// B=16, N=1536, F_IN=64, T=12, K=3, F_OUT=64
//
// Stage 1: y[b,k,c,n] = sum_f x*Theta (bf16), Theta[k] staged in LDS per k.
// Stage 2: out[b][m][c] = sum_(k,n) W[n,m]*Y[c,n], W=cheb*At on the fly.
//   Two raw barriers per K-step, COUNTED vmcnt (never 0 in-loop): Y-DMA
//   drains 1 step after issue; At regs dist-2 (2 slots), cheb dist-1.

#define B_    16
#define N_    1536
#define T_    12
#define K_    3
#define C_    768   // FOUT*T
#define NN_ ((size_t)N_ * N_)
#define CN_ ((size_t)C_ * N_)

typedef float          f32x4 __attribute__((ext_vector_type(4)));
typedef short          s16x8 __attribute__((ext_vector_type(8)));
typedef unsigned short u16x4 __attribute__((ext_vector_type(4)));

__device__ __forceinline__ unsigned short f2bf(float f) {
    unsigned int u = __builtin_bit_cast(unsigned int, f);
    return (unsigned short)((u + 0x8000u) >> 16);
}

__device__ __forceinline__ void gload_lds16(const void* g, void* l) {
    __builtin_amdgcn_global_load_lds(
        (const __attribute__((address_space(1))) unsigned*)g,
        (__attribute__((address_space(3))) unsigned*)l, 16, 0, 0);
}

#define VMWAIT_(N) asm volatile("s_waitcnt vmcnt(" #N ")" ::: "memory")
#define VMWAIT(N)  VMWAIT_(N)
#define LGKM0      asm volatile("s_waitcnt lgkmcnt(0)" ::: "memory")
#define SBAR       __builtin_amdgcn_s_barrier()
#define SCHED0     __builtin_amdgcn_sched_barrier(0)

// ---------------- Stage 1: Theta transform ----------------
// grid = B*(N/16) = 1536, block 256 (oo = tid>>4, nn = tid&15), k-outer.
// x tile + Theta[k] both staged in LDS (no per-f global chain).
__global__ __launch_bounds__(256) void s1_theta(const float* __restrict__ x,
                                                const float* __restrict__ Theta,
                                                unsigned short* __restrict__ Y) {
    __shared__ __align__(16) float xt[16][772];
    __shared__ __align__(16) float tht[4096];

    int bid = blockIdx.x;
    int nc = bid % 96, b = bid / 96;
    int n0 = nc * 16;
    int tid = threadIdx.x;

    const float* xg = x + (size_t)(b * N_ + n0) * 768;
#pragma unroll
    for (int i = 0; i < 12; ++i) {
        int c = i * 256 + tid;
        int row = c / 192, col = (c % 192) * 4;
        *(f32x4*)&xt[row][col] = *(const f32x4*)(xg + (size_t)c * 4);
    }
#pragma unroll
    for (int i = 0; i < 4; ++i)   // Theta k=0
        *(f32x4*)&tht[i * 1024 + tid * 4] =
            *(const f32x4*)(Theta + i * 1024 + tid * 4);
    __syncthreads();

    int oo = tid >> 4, nn = tid & 15;
    unsigned short* yp = Y + (size_t)b * (K_ * CN_) + n0 + nn;

    for (int k = 0; k < 3; ++k) {
        float acc[4][12];
#pragma unroll
        for (int j = 0; j < 4; ++j)
#pragma unroll
            for (int t = 0; t < 12; ++t) acc[j][t] = 0.f;

        for (int f = 0; f < 64; ++f) {
            f32x4 xv0 = *(const f32x4*)&xt[nn][f * 12];
            f32x4 xv1 = *(const f32x4*)&xt[nn][f * 12 + 4];
            f32x4 xv2 = *(const f32x4*)&xt[nn][f * 12 + 8];
            f32x4 tv  = *(const f32x4*)&tht[f * 64 + oo * 4];
#pragma unroll
            for (int j = 0; j < 4; ++j) {
#pragma unroll
                for (int t = 0; t < 4; ++t) {
                    acc[j][t]     += tv[j] * xv0[t];
                    acc[j][t + 4] += tv[j] * xv1[t];
                    acc[j][t + 8] += tv[j] * xv2[t];
                }
            }
        }
#pragma unroll
        for (int j = 0; j < 4; ++j)
#pragma unroll
            for (int t = 0; t < 12; ++t) {
                int c = (oo * 4 + j) * 12 + t;
                yp[((size_t)k * C_ + c) * N_] = f2bf(acc[j][t]);
            }
        if (k < 2) {
            __syncthreads();   // all readers of tht done
#pragma unroll
            for (int i = 0; i < 4; ++i)
                *(f32x4*)&tht[i * 1024 + tid * 4] =
                    *(const f32x4*)(Theta + (size_t)(k + 1) * 4096 + i * 1024 + tid * 4);
            __syncthreads();
        }
    }
}

// ---------------- Stage 2: counted-vmcnt MFMA GEMM ----------------
__global__ __launch_bounds__(256, 3) void s2_gemm(const float* __restrict__ At,
                                                  const float* __restrict__ cheb,
                                                  const unsigned short* __restrict__ Y,
                                                  float* __restrict__ out) {
    __shared__ __align__(16) unsigned short Alds[2][128 * 40];
    __shared__ __align__(16) unsigned short Blds[2][128 * 32];

    // XCD-chunked bijective swizzle: 1152 = 8 * 144 exactly
    int hb = blockIdx.x;
    int lb = (hb & 7) * 144 + (hb >> 3);
    int mt = lb % 12;
    int ct = (lb / 12) % 6;
    int b  = lb / 72;
    int m0 = mt * 128, c0 = ct * 128;

    int tid  = threadIdx.x;
    int lane = tid & 63, wave = tid >> 6;
    int wr = (wave >> 1) * 64, wc = (wave & 1) * 64;
    int l15 = lane & 15;

    int q = tid & 7, g = tid >> 3;   // A staging: q = n-group(4), g = m-group(4)

    const float* cb = cheb + (size_t)(q * 4) * N_ + (m0 + g * 4);
    const float* ab = At + (size_t)b * NN_ + (size_t)(q * 4) * N_ + (m0 + g * 4);

    // Y DMA source (source-side XOR swizzle; LDS dest linear)
    int lrow = lane >> 2;
    int lchunk = (lane & 3) ^ (lrow & 3);
    const unsigned short* yb = Y + (size_t)(b * K_) * CN_
                               + (size_t)(c0 + wave * 16 + lrow) * N_ + lchunk * 8;

    int awb = g * 320 + q * 8;                                       // A write byte
    int ard = (wr + l15) * 80 + (lane >> 4) * 16;                    // A frag read
    int brd = (wc + l15) * 64 + (((lane >> 4) ^ (lane & 3)) << 4);   // B frag read

    f32x4 acc[4][4];
#pragma unroll
    for (int mi = 0; mi < 4; ++mi)
#pragma unroll
        for (int ci = 0; ci < 4; ++ci) acc[mi][ci] = (f32x4)0.f;

    f32x4 cv[4];            // cheb slot (dist-1)
    f32x4 av0[4], av1[4];   // At slots (dist-2, tile%2)

#define PFCV(DNT, KC) do {                                                   \
    const float* p_ = cb + (size_t)(KC) * NN_ + (size_t)(DNT) * 32 * N_;     \
    _Pragma("unroll") for (int j = 0; j < 4; ++j)                            \
        cv[j] = *(const f32x4*)(p_ + (size_t)j * N_); } while (0)

#define PFAV(AV, DNT) do {                                                   \
    const float* p_ = ab + (size_t)(DNT) * 32 * N_;                          \
    _Pragma("unroll") for (int j = 0; j < 4; ++j)                            \
        AV[j] = *(const f32x4*)(p_ + (size_t)j * N_); } while (0)

#define YDMA(PN, DNT, KC) do {                                               \
    const unsigned short* ys_ = yb + (size_t)(KC) * CN_ + (DNT) * 32;        \
    char* bl_ = (char*)Blds[PN] + wave * 1024;                               \
    gload_lds16(ys_, bl_);                                                   \
    gload_lds16(ys_ + (size_t)64 * N_, bl_ + 4096); } while (0)

#define WBUILD(PN, AV) do {                                                  \
    f32x4 w_[4];                                                             \
    _Pragma("unroll") for (int j = 0; j < 4; ++j) w_[j] = cv[j] * AV[j];     \
    _Pragma("unroll") for (int i = 0; i < 4; ++i) {                          \
        u16x4 pk_ = { f2bf(w_[0][i]), f2bf(w_[1][i]),                        \
                      f2bf(w_[2][i]), f2bf(w_[3][i]) };                      \
        *(u16x4*)((char*)Alds[PN] + awb + i * 80) = pk_; } } while (0)

// One K-step: compute buf P (tile i), stage tile i+1 into P^1,
// prefetch cv(tile i+2), av(tile i+3). NWAIT = counted vmcnt.
#define STEP(P, AVC, AVL, SD,SK, CD,CK, AD, NWAIT, DOS, DOCV, DOAV) do {     \
    if (DOS)  { YDMA((P)^1, SD, SK); WBUILD((P)^1, AVC); }                   \
    if (DOCV) { PFCV(CD, CK); }                                              \
    if (DOAV) { PFAV(AVL, AD); }                                             \
    SCHED0;                                                                  \
    LGKM0;                                                                   \
    VMWAIT(NWAIT);                                                           \
    SCHED0;                                                                  \
    SBAR;                                                                    \
    SCHED0;                                                                  \
    const char* Ab_ = (const char*)Alds[P];                                  \
    const char* Bb_ = (const char*)Blds[P];                                  \
    s16x8 af_[4], bv_[4];                                                    \
    _Pragma("unroll") for (int mi = 0; mi < 4; ++mi)                         \
        af_[mi] = *(const s16x8*)(Ab_ + ard + mi * 1280);                    \
    _Pragma("unroll") for (int ci = 0; ci < 4; ++ci)                         \
        bv_[ci] = *(const s16x8*)(Bb_ + brd + ci * 1024);                    \
    _Pragma("unroll") for (int mi = 0; mi < 4; ++mi)                         \
        _Pragma("unroll") for (int ci = 0; ci < 4; ++ci)                     \
            acc[mi][ci] = __builtin_amdgcn_mfma_f32_16x16x32_bf16(           \
                af_[mi], bv_[ci], acc[mi][ci], 0, 0, 0);                     \
    SCHED0;                                                                  \
    SBAR;                                                                    \
    SCHED0;                                                                  \
} while (0)

    // ---- prologue: tiles 0..2 regs, buf0 built; YDMA(tile0) issued LAST
    PFAV(av0, 0);        // tile0 At -> slot0 (consumed immediately)
    PFCV(0, 0);          // tile0 cheb
    WBUILD(0, av0);      // A[0] <- W(tile0)  (one-time load stall)
    PFAV(av1, 0);        // tile1 At -> slot1 (k=1: same nt0 rows)
    PFAV(av0, 0);        // tile2 At -> slot0 (nt0)
    PFCV(0, 1);          // tile1 cheb
    YDMA(0, 0, 0);       // tile0 Y -> B[0]   (LAST: step0 NWAIT = own 18)

    // ---- first 6-step block (tiles 0..5), step0 NWAIT=18
    STEP(0, av1, av1, 0,1, 0,2, 1, 18, 1,1,1);
    STEP(1, av0, av0, 0,2, 1,0, 1, 34, 1,1,1);
    STEP(0, av1, av1, 1,0, 1,1, 1, 34, 1,1,1);
    STEP(1, av0, av0, 1,1, 1,2, 2, 34, 1,1,1);
    STEP(0, av1, av1, 1,2, 2,0, 2, 34, 1,1,1);
    STEP(1, av0, av0, 2,0, 2,1, 2, 34, 1,1,1);
    cb += (size_t)64 * N_;  ab += (size_t)64 * N_;  yb += 64;

    // ---- steady: it2 = 1..22 (tiles 6..137)
#pragma unroll 1
    for (int it2 = 1; it2 < 23; ++it2) {
        STEP(0, av1, av1, 0,1, 0,2, 1, 34, 1,1,1);
        STEP(1, av0, av0, 0,2, 1,0, 1, 34, 1,1,1);
        STEP(0, av1, av1, 1,0, 1,1, 1, 34, 1,1,1);
        STEP(1, av0, av0, 1,1, 1,2, 2, 34, 1,1,1);
        STEP(0, av1, av1, 1,2, 2,0, 2, 34, 1,1,1);
        STEP(1, av0, av0, 2,0, 2,1, 2, 34, 1,1,1);
        cb += (size_t)64 * N_;  ab += (size_t)64 * N_;  yb += 64;
    }

    // ---- tail: tiles 138..143 (no OOB prefetch; exact counts 26,10,0)
    STEP(0, av1, av1, 0,1, 0,2, 1, 34, 1,1,1);
    STEP(1, av0, av0, 0,2, 1,0, 1, 34, 1,1,1);
    STEP(0, av1, av1, 1,0, 1,1, 1, 34, 1,1,1);
    STEP(1, av0, av0, 1,1, 1,2, 0, 26, 1,1,0);
    STEP(0, av1, av1, 1,2, 0,0, 0, 10, 1,0,0);
    STEP(1, av0, av0, 0,0, 0,0, 0,  0, 0,0,0);

#undef PFCV
#undef PFAV
#undef YDMA
#undef WBUILD
#undef STEP

    // ---- epilogue: relu + store (D: col=lane&15, row=(lane>>4)*4+r)
    int rbase = (lane >> 4) * 4;
#pragma unroll
    for (int mi = 0; mi < 4; ++mi) {
#pragma unroll
        for (int ci = 0; ci < 4; ++ci) {
            int m = m0 + wr + mi * 16 + rbase;
            int c = c0 + wc + ci * 16 + l15;
            float* op = out + (size_t)(b * N_ + m) * C_ + c;
#pragma unroll
            for (int r = 0; r < 4; ++r) {
                float v = acc[mi][ci][r];
                op[(size_t)r * C_] = v > 0.f ? v : 0.f;
            }
        }
    }
}

extern "C" void kernel_launch(void* const* d_in, const int* in_sizes, int n_in,
                              void* d_out, int out_size, void* d_ws, size_t ws_size,
                              hipStream_t stream) {
    const float* x    = (const float*)d_in[0];
    const float* At   = (const float*)d_in[1];
    const float* cheb = (const float*)d_in[2];
    const float* Th   = (const float*)d_in[3];
    unsigned short* Y = (unsigned short*)d_ws;   // 16*3*768*1536*2 = 113 MB
    float* out = (float*)d_out;

    s1_theta<<<dim3(B_ * 96),     dim3(256), 0, stream>>>(x, Th, Y);
    s2_gemm <<<dim3(B_ * 12 * 6), dim3(256), 0, stream>>>(At, cheb, Y, out);
}